// Round 7
// baseline (135.551 us; speedup 1.0000x reference)
//
#include <hip/hip_runtime.h>
#include <hip/hip_bf16.h>

// Problem constants
#define Bq   4
#define Cc   64
#define Hh   160
#define Ww   160
#define HWp  (Hh * Ww)          // 25600
#define COUTc 64

typedef __attribute__((ext_vector_type(8))) short bf16x8;
typedef __attribute__((ext_vector_type(4))) float f32x4;
typedef __attribute__((ext_vector_type(2))) float f32x2;
typedef __attribute__((ext_vector_type(4))) int   int4v;

// ws layout (shorts):
//   wTb   [o][tap*64+c]   o<64  : 64*576
//   wToffb[oc][tap*64+c]  oc<32 : 32*576 (cols 18..31 zero)
//   xcl   [b][y][x][c]          : 4*25600*64 + 64 (zero pad pixel at end)
#define WTB_SHORTS   (64 * 576)
#define WTOFF_SHORTS (32 * 576)
#define XCL_OFS      (WTB_SHORTS + WTOFF_SHORTS)
#define XCL_PIX      ((size_t)Bq * HWp)            // index of zero pad pixel
#define XCL_SHORTS   (XCL_PIX * 64 + 64)

__device__ __forceinline__ short f2bf(float f) {
    union { float f; unsigned u; } v; v.f = f;
    unsigned r = v.u + 0x7fffu + ((v.u >> 16) & 1u);   // RNE
    return (short)(r >> 16);
}
__device__ __forceinline__ float bflo(unsigned u) {
    union { unsigned u; float f; } v; v.u = u << 16; return v.f;
}
__device__ __forceinline__ float bfhi(unsigned u) {
    union { unsigned u; float f; } v; v.u = u & 0xffff0000u; return v.f;
}
__device__ __forceinline__ unsigned pk2(float lo, float hi) {
    union { __hip_bfloat162 h; unsigned u; } v;
    v.h = __float22bfloat162_rn(float2{lo, hi});       // v_cvt_pk_bf16_f32
    return v.u;
}

// ---------------------------------------------------------------------------
// Merged prep: blocks [0,400) xcl image; [400,544) weight images; 544 zero pad.
// ---------------------------------------------------------------------------
__global__ __launch_bounds__(256) void prep_all(const float* __restrict__ x,
                                                const float* __restrict__ w,
                                                const float* __restrict__ w_off,
                                                short* __restrict__ ws) {
    int blk = blockIdx.x;
    int tid = threadIdx.x;
    if (blk < 400) {
        int g = blk * 256 + tid;             // pixel id
        int b = g / HWp, p = g - b * HWp;
        const float* xp = x + (size_t)b * Cc * HWp + p;
        short* op = ws + XCL_OFS + (size_t)g * 64;
#pragma unroll
        for (int cg = 0; cg < 8; ++cg) {
            unsigned d[4];
#pragma unroll
            for (int dj = 0; dj < 4; ++dj) {
                float f0 = xp[(size_t)(cg * 8 + 2 * dj) * HWp];
                float f1 = xp[(size_t)(cg * 8 + 2 * dj + 1) * HWp];
                d[dj] = pk2(f0, f1);
            }
            *(int4v*)(op + cg * 8) = *(int4v*)d;
        }
    } else if (blk < 544) {
        int i = (blk - 400) * 256 + tid;
        if (i < WTB_SHORTS) {
            int o = i / 576, rem = i - o * 576;
            int t = rem >> 6, c = rem & 63;
            ws[i] = f2bf(w[o * 576 + c * 9 + t]);
        }
        if (i < WTOFF_SHORTS) {
            int oc = i / 576, rem = i - oc * 576;
            int t = rem >> 6, c = rem & 63;
            float v = (oc < 18) ? w_off[oc * 576 + c * 9 + t] : 0.f;
            ws[WTB_SHORTS + i] = f2bf(v);
        }
    } else {
        // zero pad pixel (128 B)
        if (tid < 8)
            *(int4v*)((char*)(ws + XCL_OFS) + XCL_PIX * 128 + tid * 16) =
                (int4v){0, 0, 0, 0};
    }
}

// ---------------------------------------------------------------------------
// Bilinear table for one tap of one pixel.
// ---------------------------------------------------------------------------
__device__ __forceinline__ void tbl_one(const float* __restrict__ ob, int t,
                                        int y, int xpix, int* ad, f32x4* wg) {
    int ty = t / 3, tx = t % 3;
    f32x2 d2 = *(const f32x2*)(ob + 2 * t);
    float py  = (float)(y - 1 + ty) + d2[0];
    float pxf = (float)(xpix - 1 + tx) + d2[1];
    float fy = floorf(py), fx = floorf(pxf);
    float ly = py - fy, lx = pxf - fx;
    int iy0 = (int)fy, ix0 = (int)fx;
    int iy1 = iy0 + 1, ix1 = ix0 + 1;
    bool vy0 = (iy0 >= 0) && (iy0 < Hh);
    bool vy1 = (iy1 >= 0) && (iy1 < Hh);
    bool vx0 = (ix0 >= 0) && (ix0 < Ww);
    bool vx1 = (ix1 >= 0) && (ix1 < Ww);
    int cy0 = min(max(iy0, 0), Hh - 1), cy1 = min(max(iy1, 0), Hh - 1);
    int cx0 = min(max(ix0, 0), Ww - 1), cx1 = min(max(ix1, 0), Ww - 1);
    ad[0] = (cy0 * Ww + cx0) * 128;
    ad[1] = (cy0 * Ww + cx1) * 128;
    ad[2] = (cy1 * Ww + cx0) * 128;
    ad[3] = (cy1 * Ww + cx1) * 128;
    (*wg)[0] = (vy0 && vx0) ? (1.f - ly) * (1.f - lx) : 0.f;
    (*wg)[1] = (vy0 && vx1) ? (1.f - ly) * lx         : 0.f;
    (*wg)[2] = (vy1 && vx0) ? ly * (1.f - lx)         : 0.f;
    (*wg)[3] = (vy1 && vx1) ? ly * lx                 : 0.f;
}

__device__ __forceinline__ void bil_consume(const bf16x8* __restrict__ st,
                                            f32x4 wg, short* __restrict__ dst) {
    union { bf16x8 v; unsigned u[4]; } U0, U1, U2, U3;
    U0.v = st[0]; U1.v = st[1]; U2.v = st[2]; U3.v = st[3];
    union { unsigned u[4]; bf16x8 v; } A;
#pragma unroll
    for (int d = 0; d < 4; ++d) {
        f32x2 v0 = {bflo(U0.u[d]), bfhi(U0.u[d])};
        f32x2 v1 = {bflo(U1.u[d]), bfhi(U1.u[d])};
        f32x2 v2 = {bflo(U2.u[d]), bfhi(U2.u[d])};
        f32x2 v3 = {bflo(U3.u[d]), bfhi(U3.u[d])};
        f32x2 s = v0 * wg[0] + v1 * wg[1] + v2 * wg[2] + v3 * wg[3];
        A.u[d] = pk2(s[0], s[1]);
    }
    *(bf16x8*)dst = A.v;
}

// ---------------------------------------------------------------------------
// Sample NT taps: 2-deep pipeline, sched_barrier(0) fences prevent load-sink.
// thread = (px = tid>>3, cg = tid&7), cb = cg*16 byte channel offset.
// ---------------------------------------------------------------------------
template<int T0, int NT>
__device__ __forceinline__ void sample_taps(const char* __restrict__ xclb,
                                            const float* __restrict__ ob,
                                            short (*__restrict__ sm)[32][72],
                                            int px, int cb, int y, int xpix) {
    int    ad[2][4];
    f32x4  wg[2];
    bf16x8 stg[2][4];
    tbl_one(ob, T0, y, xpix, ad[0], &wg[0]);
#pragma unroll
    for (int c = 0; c < 4; ++c)
        stg[0][c] = *(const bf16x8*)(xclb + ad[0][c] + cb);
#pragma unroll
    for (int ti = 0; ti < NT; ++ti) {
        if (ti + 1 < NT) {
            const int ns = (ti + 1) & 1;
            tbl_one(ob, T0 + ti + 1, y, xpix, ad[ns], &wg[ns]);
#pragma unroll
            for (int c = 0; c < 4; ++c)
                stg[ns][c] = *(const bf16x8*)(xclb + ad[ns][c] + cb);
        }
        __builtin_amdgcn_sched_barrier(0);
        const int cs = ti & 1;
        bil_consume(stg[cs], wg[cs], (short*)((char*)&sm[ti][px][0] + cb));
    }
}

// ---------------------------------------------------------------------------
// GEMM NT taps from sm; 1-unit-ahead prefetch of A(LDS) + B(global) fragments.
// ---------------------------------------------------------------------------
template<int T0, int NT>
__device__ __forceinline__ void gemm_taps(const short (*__restrict__ sm)[32][72],
                                          f32x4* acc, int px_t, int lg,
                                          const short* __restrict__ wb0,
                                          const short* __restrict__ wb1) {
    bf16x8 sa[2], s0[2], s1[2];
    sa[0] = *(const bf16x8*)(&sm[0][px_t][lg * 8]);
    s0[0] = *(const bf16x8*)(wb0 + T0 * 64 + lg * 8);
    s1[0] = *(const bf16x8*)(wb1 + T0 * 64 + lg * 8);
#pragma unroll
    for (int u = 0; u < 2 * NT; ++u) {
        if (u + 1 < 2 * NT) {
            const int ti = (u + 1) >> 1, h = (u + 1) & 1, ns = (u + 1) & 1;
            sa[ns] = *(const bf16x8*)(&sm[ti][px_t][h * 32 + lg * 8]);
            s0[ns] = *(const bf16x8*)(wb0 + (T0 + ti) * 64 + h * 32 + lg * 8);
            s1[ns] = *(const bf16x8*)(wb1 + (T0 + ti) * 64 + h * 32 + lg * 8);
        }
        __builtin_amdgcn_sched_barrier(0);
        const int cs = u & 1;
        acc[0] = __builtin_amdgcn_mfma_f32_16x16x32_bf16(sa[cs], s0[cs], acc[0], 0, 0, 0);
        acc[1] = __builtin_amdgcn_mfma_f32_16x16x32_bf16(sa[cs], s1[cs], acc[1], 0, 0, 0);
    }
}

// ---------------------------------------------------------------------------
// Fused kernel: 32-pixel tile; K-halved LDS im2col; pipelined gathers.
// ---------------------------------------------------------------------------
__global__ __launch_bounds__(256, 4) void fused_cl(const short* __restrict__ ws,
                                                   const float* __restrict__ b_off,
                                                   const float* __restrict__ bias,
                                                   float* __restrict__ out) {
    __shared__ short sm[5][32][72];     // K-half im2col, padded rows (144 B)
    __shared__ float offbuf[32][20];

    int tid = threadIdx.x;
    int wid = tid >> 6;
    int l   = tid & 63;
    int lr  = l & 15;
    int lg  = l >> 4;
    int mhalf = wid >> 1;
    int nhalf = wid & 1;

    // XCD-aware swizzle: nwg = 3200, 3200 % 8 == 0 -> bijective
    int bid = blockIdx.x;
    int g_blk = (bid & 7) * 400 + (bid >> 3);

    int pix_base = g_blk * 32;
    int b   = pix_base / HWp;
    int rem = pix_base - b * HWp;
    int y   = rem / Ww;
    int x0  = rem - y * Ww;            // multiple of 32, row-aligned

    const short* wTb    = ws;
    const short* wToffb = ws + WTB_SHORTS;
    const char*  xclb   = (const char*)(ws + XCL_OFS) + (size_t)b * HWp * 128;
    const int zoff = (int)((Bq - b) * (size_t)HWp * 128);   // zero pad pixel

    // ---------------- Phase 1: offset GEMM (2-deep tap pipeline) ----------
    {
        int px_t1 = mhalf * 16 + lr;
        int xpix  = x0 + px_t1;
        int poff[9];
#pragma unroll
        for (int ty = 0; ty < 3; ++ty) {
#pragma unroll
            for (int tx = 0; tx < 3; ++tx) {
                int t  = ty * 3 + tx;
                int yy = y - 1 + ty;
                bool vy = (yy >= 0) && (yy < Hh);
                int yc = min(max(yy, 0), Hh - 1);
                int xx = xpix - 1 + tx;
                bool vx = (xx >= 0) && (xx < Ww);
                int xc = min(max(xx, 0), Ww - 1);
                poff[t] = (vy && vx) ? (yc * Ww + xc) * 128 : zoff;
            }
        }
        int oc_row = nhalf * 16 + lr;
        const char* wor = (const char*)wToffb + (size_t)oc_row * 1152;
        f32x4 accA = {0.f, 0.f, 0.f, 0.f};
        f32x4 accB = {0.f, 0.f, 0.f, 0.f};
        bf16x8 sa2[2][2], sb2[2][2];
        {
            const char* q = xclb + poff[0] + lg * 16;
            sa2[0][0] = *(const bf16x8*)(q);
            sa2[0][1] = *(const bf16x8*)(q + 64);
            sb2[0][0] = *(const bf16x8*)(wor + lg * 16);
            sb2[0][1] = *(const bf16x8*)(wor + 64 + lg * 16);
        }
#pragma unroll
        for (int t = 0; t < 9; ++t) {
            if (t < 8) {
                const int ns = (t + 1) & 1;
                const char* q = xclb + poff[t + 1] + lg * 16;
                sa2[ns][0] = *(const bf16x8*)(q);
                sa2[ns][1] = *(const bf16x8*)(q + 64);
                const char* wq = wor + (t + 1) * 128 + lg * 16;
                sb2[ns][0] = *(const bf16x8*)(wq);
                sb2[ns][1] = *(const bf16x8*)(wq + 64);
            }
            __builtin_amdgcn_sched_barrier(0);
            const int cs = t & 1;
            accA = __builtin_amdgcn_mfma_f32_16x16x32_bf16(sa2[cs][0], sb2[cs][0], accA, 0, 0, 0);
            accB = __builtin_amdgcn_mfma_f32_16x16x32_bf16(sa2[cs][1], sb2[cs][1], accB, 0, 0, 0);
        }
        if (oc_row < 18) {
            float bv = b_off[oc_row];
#pragma unroll
            for (int j = 0; j < 4; ++j)
                offbuf[mhalf * 16 + lg * 4 + j][oc_row] = accA[j] + accB[j] + bv;
        }
    }
    __syncthreads();

    // ---------------- Phases 3a/3b, two K-halves ----------
    int px = tid >> 3;          // 0..31
    int cg = tid & 7;
    int cb = cg * 16;
    int xpix2 = x0 + px;
    const float* ob = offbuf[px];

    f32x4 acc[2];
    acc[0] = (f32x4){0.f, 0.f, 0.f, 0.f};
    acc[1] = (f32x4){0.f, 0.f, 0.f, 0.f};
    int px_t = mhalf * 16 + lr;
    const short* wb0 = wTb + (size_t)(nhalf * 32 + lr) * 576;
    const short* wb1 = wTb + (size_t)(nhalf * 32 + 16 + lr) * 576;

    // half 0: taps 0..4
    sample_taps<0, 5>(xclb, ob, sm, px, cb, y, xpix2);
    __syncthreads();
    gemm_taps<0, 5>(sm, acc, px_t, lg, wb0, wb1);
    __syncthreads();

    // half 1: taps 5..8
    sample_taps<5, 4>(xclb, ob, sm, px, cb, y, xpix2);
    __syncthreads();
    gemm_taps<5, 4>(sm, acc, px_t, lg, wb0, wb1);

    // ---------------- Epilogue ----------------
    float* obase = out + (size_t)b * COUTc * HWp + y * Ww + x0;
#pragma unroll
    for (int nt = 0; nt < 2; ++nt) {
        int o = nhalf * 32 + nt * 16 + lr;
        float bv = bias[o];
#pragma unroll
        for (int j = 0; j < 4; ++j)
            obase[(size_t)o * HWp + mhalf * 16 + lg * 4 + j] = acc[nt][j] + bv;
    }
}

// ---------------------------------------------------------------------------
extern "C" void kernel_launch(void* const* d_in, const int* in_sizes, int n_in,
                              void* d_out, int out_size, void* d_ws, size_t ws_size,
                              hipStream_t stream) {
    const float* x      = (const float*)d_in[0];
    const float* w_off  = (const float*)d_in[1];
    const float* b_off  = (const float*)d_in[2];
    const float* weight = (const float*)d_in[3];
    const float* bias   = (const float*)d_in[4];
    float* outp = (float*)d_out;
    short* ws   = (short*)d_ws;

    // 400 blocks xcl + 144 blocks weights + 1 block zero pad
    prep_all<<<545, 256, 0, stream>>>(x, weight, w_off, ws);

    int nblocks = (Bq * HWp) / 32;   // 3200 workgroups, 32 pixels each
    fused_cl<<<nblocks, 256, 0, stream>>>(ws, b_off, bias, outp);
}

// Round 8
// 80.105 us; speedup vs baseline: 1.6922x; 1.6922x over previous
//
#include <hip/hip_runtime.h>
#include <hip/hip_bf16.h>

// Problem constants
#define Bq   4
#define Cc   64
#define Hh   160
#define Ww   160
#define HWp  (Hh * Ww)          // 25600
#define COUTc 64

typedef __attribute__((ext_vector_type(8))) short bf16x8;
typedef __attribute__((ext_vector_type(4))) float f32x4;
typedef __attribute__((ext_vector_type(2))) float f32x2;
typedef __attribute__((ext_vector_type(4))) int   int4v;

// ws layout (shorts):
//   wTbF  : 72 frags x 512 shorts  (main weights, fragment-major)
//           frag fidx = (tap*2+h)*4 + cg ; element l*8+j =
//           w[o=cg*16+(l&15)][c=h*32+(l>>4)*8+j][tap]
//   wToffF: 36 frags x 512 shorts  (offset weights, fragment-major)
//           frag fidx = (tap*2+h)*2 + g ; element l*8+j =
//           w_off[oc=g*16+(l&15)][c][tap]  (oc>=18 -> 0)
//   xcl   [b][y][x][c] : 4*25600*64 + 64 (zero pad pixel at end)
#define WTBF_SHORTS   (72 * 512)                    // 36864
#define WTOFFF_SHORTS (36 * 512)                    // 18432
#define XCL_OFS       (WTBF_SHORTS + WTOFFF_SHORTS) // 55296
#define XCL_PIX       ((size_t)Bq * HWp)            // zero pad pixel index
#define XCL_SHORTS    (XCL_PIX * 64 + 64)

__device__ __forceinline__ short f2bf(float f) {
    union { float f; unsigned u; } v; v.f = f;
    unsigned r = v.u + 0x7fffu + ((v.u >> 16) & 1u);   // RNE
    return (short)(r >> 16);
}
__device__ __forceinline__ float bflo(unsigned u) {
    union { unsigned u; float f; } v; v.u = u << 16; return v.f;
}
__device__ __forceinline__ float bfhi(unsigned u) {
    union { unsigned u; float f; } v; v.u = u & 0xffff0000u; return v.f;
}
__device__ __forceinline__ unsigned pk2(float lo, float hi) {
    union { __hip_bfloat162 h; unsigned u; } v;
    v.h = __float22bfloat162_rn(float2{lo, hi});       // v_cvt_pk_bf16_f32
    return v.u;
}

// ---------------------------------------------------------------------------
// Merged prep: [0,400) xcl image; [400,544) fragment-major weights; 544 pad.
// ---------------------------------------------------------------------------
__global__ __launch_bounds__(256) void prep_all(const float* __restrict__ x,
                                                const float* __restrict__ w,
                                                const float* __restrict__ w_off,
                                                short* __restrict__ ws) {
    int blk = blockIdx.x;
    int tid = threadIdx.x;
    if (blk < 400) {
        int g = blk * 256 + tid;             // pixel id
        int b = g / HWp, p = g - b * HWp;
        const float* xp = x + (size_t)b * Cc * HWp + p;
        short* op = ws + XCL_OFS + (size_t)g * 64;
#pragma unroll
        for (int cg = 0; cg < 8; ++cg) {
            unsigned d[4];
#pragma unroll
            for (int dj = 0; dj < 4; ++dj) {
                float f0 = xp[(size_t)(cg * 8 + 2 * dj) * HWp];
                float f1 = xp[(size_t)(cg * 8 + 2 * dj + 1) * HWp];
                d[dj] = pk2(f0, f1);
            }
            *(int4v*)(op + cg * 8) = *(int4v*)d;
        }
    } else if (blk < 544) {
        int i = (blk - 400) * 256 + tid;
        if (i < WTBF_SHORTS) {
            int fidx = i >> 9, r = i & 511;
            int l = r >> 3, j = r & 7;
            int cg = fidx & 3, th = fidx >> 2;
            int tap = th >> 1, h = th & 1;
            int o = cg * 16 + (l & 15);
            int c = h * 32 + ((l >> 4) << 3) + j;
            ws[i] = f2bf(w[o * 576 + c * 9 + tap]);
        }
        if (i < WTOFFF_SHORTS) {
            int fidx = i >> 9, r = i & 511;
            int l = r >> 3, j = r & 7;
            int g = fidx & 1, th = fidx >> 1;
            int tap = th >> 1, h = th & 1;
            int oc = g * 16 + (l & 15);
            int c = h * 32 + ((l >> 4) << 3) + j;
            float v = (oc < 18) ? w_off[oc * 576 + c * 9 + tap] : 0.f;
            ws[WTBF_SHORTS + i] = f2bf(v);
        }
    } else {
        if (tid < 8)
            *(int4v*)((char*)(ws + XCL_OFS) + XCL_PIX * 128 + tid * 16) =
                (int4v){0, 0, 0, 0};
    }
}

// ---------------------------------------------------------------------------
// Bilinear table for one tap of one pixel.
// ---------------------------------------------------------------------------
__device__ __forceinline__ void tbl_one(const float* __restrict__ ob, int t,
                                        int y, int xpix, int* ad, f32x4* wg) {
    int ty = t / 3, tx = t % 3;
    f32x2 d2 = *(const f32x2*)(ob + 2 * t);
    float py  = (float)(y - 1 + ty) + d2[0];
    float pxf = (float)(xpix - 1 + tx) + d2[1];
    float fy = floorf(py), fx = floorf(pxf);
    float ly = py - fy, lx = pxf - fx;
    int iy0 = (int)fy, ix0 = (int)fx;
    int iy1 = iy0 + 1, ix1 = ix0 + 1;
    bool vy0 = (iy0 >= 0) && (iy0 < Hh);
    bool vy1 = (iy1 >= 0) && (iy1 < Hh);
    bool vx0 = (ix0 >= 0) && (ix0 < Ww);
    bool vx1 = (ix1 >= 0) && (ix1 < Ww);
    int cy0 = min(max(iy0, 0), Hh - 1), cy1 = min(max(iy1, 0), Hh - 1);
    int cx0 = min(max(ix0, 0), Ww - 1), cx1 = min(max(ix1, 0), Ww - 1);
    ad[0] = (cy0 * Ww + cx0) * 128;
    ad[1] = (cy0 * Ww + cx1) * 128;
    ad[2] = (cy1 * Ww + cx0) * 128;
    ad[3] = (cy1 * Ww + cx1) * 128;
    (*wg)[0] = (vy0 && vx0) ? (1.f - ly) * (1.f - lx) : 0.f;
    (*wg)[1] = (vy0 && vx1) ? (1.f - ly) * lx         : 0.f;
    (*wg)[2] = (vy1 && vx0) ? ly * (1.f - lx)         : 0.f;
    (*wg)[3] = (vy1 && vx1) ? ly * lx                 : 0.f;
}

__device__ __forceinline__ void bil_consume(const bf16x8* __restrict__ st,
                                            f32x4 wg, short* __restrict__ dst) {
    union { bf16x8 v; unsigned u[4]; } U0, U1, U2, U3;
    U0.v = st[0]; U1.v = st[1]; U2.v = st[2]; U3.v = st[3];
    union { unsigned u[4]; bf16x8 v; } A;
#pragma unroll
    for (int d = 0; d < 4; ++d) {
        f32x2 v0 = {bflo(U0.u[d]), bfhi(U0.u[d])};
        f32x2 v1 = {bflo(U1.u[d]), bfhi(U1.u[d])};
        f32x2 v2 = {bflo(U2.u[d]), bfhi(U2.u[d])};
        f32x2 v3 = {bflo(U3.u[d]), bfhi(U3.u[d])};
        f32x2 s = v0 * wg[0] + v1 * wg[1] + v2 * wg[2] + v3 * wg[3];
        A.u[d] = pk2(s[0], s[1]);
    }
    *(bf16x8*)dst = A.v;
}

// ---------------------------------------------------------------------------
// Sample NT taps, 4-deep corner-load pipeline (16 loads in flight).
// thread = (px = tid>>3, cg = tid&7), cb = cg*16 byte channel offset.
// ---------------------------------------------------------------------------
template<int T0, int NT>
__device__ __forceinline__ void sample_taps(const char* __restrict__ xclb,
                                            const float* __restrict__ ob,
                                            short (*__restrict__ sm)[32][72],
                                            int px, int cb, int y, int xpix) {
    f32x4  wgq[4];
    bf16x8 stq[4][4];
    constexpr int PD = (NT < 4) ? NT : 4;
#pragma unroll
    for (int s = 0; s < PD; ++s) {
        int ad[4];
        tbl_one(ob, T0 + s, y, xpix, ad, &wgq[s]);
#pragma unroll
        for (int c = 0; c < 4; ++c)
            stq[s][c] = *(const bf16x8*)(xclb + ad[c] + cb);
    }
#pragma unroll
    for (int ti = 0; ti < NT; ++ti) {
        const int s = ti & 3;
        bil_consume(stq[s], wgq[s], (short*)((char*)&sm[ti][px][0] + cb));
        if (ti + 4 < NT) {
            int ad[4];
            tbl_one(ob, T0 + ti + 4, y, xpix, ad, &wgq[s]);
#pragma unroll
            for (int c = 0; c < 4; ++c)
                stq[s][c] = *(const bf16x8*)(xclb + ad[c] + cb);
        }
        __builtin_amdgcn_sched_barrier(0);
    }
}

// ---------------------------------------------------------------------------
// GEMM NT taps from sm; fragment-major coalesced weight loads, 1-unit ahead.
// wfb = wTbF + nhalf*1024 + l*8 (shorts)
// ---------------------------------------------------------------------------
template<int T0, int NT>
__device__ __forceinline__ void gemm_taps(const short (*__restrict__ sm)[32][72],
                                          f32x4* acc, int px_t, int lg,
                                          const short* __restrict__ wfb) {
    bf16x8 sa[2], s0[2], s1[2];
    sa[0] = *(const bf16x8*)(&sm[0][px_t][lg * 8]);
    s0[0] = *(const bf16x8*)(wfb + (T0 * 2) * 2048);
    s1[0] = *(const bf16x8*)(wfb + (T0 * 2) * 2048 + 512);
#pragma unroll
    for (int u = 0; u < 2 * NT; ++u) {
        if (u + 1 < 2 * NT) {
            const int ti = (u + 1) >> 1, h = (u + 1) & 1, ns = (u + 1) & 1;
            sa[ns] = *(const bf16x8*)(&sm[ti][px_t][h * 32 + lg * 8]);
            s0[ns] = *(const bf16x8*)(wfb + ((T0 + ti) * 2 + h) * 2048);
            s1[ns] = *(const bf16x8*)(wfb + ((T0 + ti) * 2 + h) * 2048 + 512);
        }
        __builtin_amdgcn_sched_barrier(0);
        const int cs = u & 1;
        acc[0] = __builtin_amdgcn_mfma_f32_16x16x32_bf16(sa[cs], s0[cs], acc[0], 0, 0, 0);
        acc[1] = __builtin_amdgcn_mfma_f32_16x16x32_bf16(sa[cs], s1[cs], acc[1], 0, 0, 0);
    }
}

// ---------------------------------------------------------------------------
// Fused kernel: 32-pixel tile; 4-deep pipelined gathers; coalesced weights.
// ---------------------------------------------------------------------------
__global__ __launch_bounds__(256, 4) void fused_cl(const short* __restrict__ ws,
                                                   const float* __restrict__ b_off,
                                                   const float* __restrict__ bias,
                                                   float* __restrict__ out) {
    __shared__ short sm[5][32][72];     // K-half im2col, padded rows (144 B)
    __shared__ float offbuf[32][20];

    int tid = threadIdx.x;
    int wid = tid >> 6;
    int l   = tid & 63;
    int lr  = l & 15;
    int lg  = l >> 4;
    int mhalf = wid >> 1;
    int nhalf = wid & 1;

    // XCD-aware swizzle: nwg = 3200, 3200 % 8 == 0 -> bijective
    int bid = blockIdx.x;
    int g_blk = (bid & 7) * 400 + (bid >> 3);

    int pix_base = g_blk * 32;
    int b   = pix_base / HWp;
    int rem = pix_base - b * HWp;
    int y   = rem / Ww;
    int x0  = rem - y * Ww;            // multiple of 32, row-aligned

    const short* wTbF   = ws;
    const short* wToffF = ws + WTBF_SHORTS;
    const char*  xclb   = (const char*)(ws + XCL_OFS) + (size_t)b * HWp * 128;
    const int zoff = (int)((Bq - b) * (size_t)HWp * 128);   // zero pad pixel

    // ---------------- Phase 1: offset GEMM (4-deep pipeline) --------------
    {
        int px_t1 = mhalf * 16 + lr;
        int xpix  = x0 + px_t1;
        int poff[9];
#pragma unroll
        for (int ty = 0; ty < 3; ++ty) {
#pragma unroll
            for (int tx = 0; tx < 3; ++tx) {
                int t  = ty * 3 + tx;
                int yy = y - 1 + ty;
                bool vy = (yy >= 0) && (yy < Hh);
                int yc = min(max(yy, 0), Hh - 1);
                int xx = xpix - 1 + tx;
                bool vx = (xx >= 0) && (xx < Ww);
                int xc = min(max(xx, 0), Ww - 1);
                poff[t] = (vy && vx) ? (yc * Ww + xc) * 128 : zoff;
            }
        }
        // B-frag base: frag (t,h,g=nhalf) at ((t*2+h)*2+nhalf)*512 + l*8
        const short* wofr = wToffF + (size_t)nhalf * 512 + l * 8;
        f32x4 accA = {0.f, 0.f, 0.f, 0.f};
        f32x4 accB = {0.f, 0.f, 0.f, 0.f};
        bf16x8 sA[4], sB[4];
#pragma unroll
        for (int u = 0; u < 4; ++u) {
            const int t = u >> 1, h = u & 1;
            sA[u] = *(const bf16x8*)(xclb + poff[t] + lg * 16 + h * 64);
            sB[u] = *(const bf16x8*)(wofr + u * 1024);
        }
#pragma unroll
        for (int u = 0; u < 18; ++u) {
            const int s = u & 3;
            if (u & 1)
                accB = __builtin_amdgcn_mfma_f32_16x16x32_bf16(sA[s], sB[s], accB, 0, 0, 0);
            else
                accA = __builtin_amdgcn_mfma_f32_16x16x32_bf16(sA[s], sB[s], accA, 0, 0, 0);
            if (u + 4 < 18) {
                const int un = u + 4, t = un >> 1, h = un & 1;
                sA[s] = *(const bf16x8*)(xclb + poff[t] + lg * 16 + h * 64);
                sB[s] = *(const bf16x8*)(wofr + un * 1024);
            }
            __builtin_amdgcn_sched_barrier(0);
        }
        int oc_row = nhalf * 16 + lr;
        if (oc_row < 18) {
            float bv = b_off[oc_row];
#pragma unroll
            for (int j = 0; j < 4; ++j)
                offbuf[mhalf * 16 + lg * 4 + j][oc_row] = accA[j] + accB[j] + bv;
        }
    }
    __syncthreads();

    // ---------------- Sample + GEMM, two K-halves ----------
    int px = tid >> 3;          // 0..31
    int cg = tid & 7;
    int cb = cg * 16;
    int xpix2 = x0 + px;
    const float* ob = offbuf[px];

    f32x4 acc[2];
    acc[0] = (f32x4){0.f, 0.f, 0.f, 0.f};
    acc[1] = (f32x4){0.f, 0.f, 0.f, 0.f};
    int px_t = mhalf * 16 + lr;
    const short* wfb = wTbF + (size_t)nhalf * 1024 + l * 8;

    // half 0: taps 0..4
    sample_taps<0, 5>(xclb, ob, sm, px, cb, y, xpix2);
    __syncthreads();
    gemm_taps<0, 5>(sm, acc, px_t, lg, wfb);
    __syncthreads();

    // half 1: taps 5..8
    sample_taps<5, 4>(xclb, ob, sm, px, cb, y, xpix2);
    __syncthreads();
    gemm_taps<5, 4>(sm, acc, px_t, lg, wfb);

    // ---------------- Epilogue ----------------
    float* obase = out + (size_t)b * COUTc * HWp + y * Ww + x0;
#pragma unroll
    for (int nt = 0; nt < 2; ++nt) {
        int o = nhalf * 32 + nt * 16 + lr;
        float bv = bias[o];
#pragma unroll
        for (int j = 0; j < 4; ++j)
            obase[(size_t)o * HWp + mhalf * 16 + lg * 4 + j] = acc[nt][j] + bv;
    }
}

// ---------------------------------------------------------------------------
extern "C" void kernel_launch(void* const* d_in, const int* in_sizes, int n_in,
                              void* d_out, int out_size, void* d_ws, size_t ws_size,
                              hipStream_t stream) {
    const float* x      = (const float*)d_in[0];
    const float* w_off  = (const float*)d_in[1];
    const float* b_off  = (const float*)d_in[2];
    const float* weight = (const float*)d_in[3];
    const float* bias   = (const float*)d_in[4];
    float* outp = (float*)d_out;
    short* ws   = (short*)d_ws;

    // 400 blocks xcl + 144 blocks weights + 1 block zero pad
    prep_all<<<545, 256, 0, stream>>>(x, weight, w_off, ws);

    int nblocks = (Bq * HWp) / 32;   // 3200 workgroups, 32 pixels each
    fused_cl<<<nblocks, 256, 0, stream>>>(ws, b_off, bias, outp);
}